// Round 1
// 572.736 us; speedup vs baseline: 1.0255x; 1.0255x over previous
//
#include <hip/hip_runtime.h>

#define IN_C 128
#define HEADS 4
#define OUT_C 64
#define OUT_F 256   // HEADS*OUT_C
#define NEG_SLOPE 0.2f
#define BN_EPS 1e-5f
#define NBUCK 64

typedef __attribute__((ext_vector_type(8))) short short8;
typedef __attribute__((ext_vector_type(4))) float floatx4;

__device__ __forceinline__ unsigned short f2bf(float f) {
    unsigned u = __float_as_uint(f);
    u += 0x7FFF + ((u >> 16) & 1);   // round-to-nearest-even
    return (unsigned short)(u >> 16);
}
__device__ __forceinline__ float bf2f(unsigned short u) {
    return __uint_as_float(((unsigned)u) << 16);
}

// ---------------- Wp prep: fragment-ordered bf16 weights ----------------
// Wp[((w*4+kt)*4+nt)*512 + l*8 + j] = bf16( W[(kt*32+(l>>4)*8+j) * OUT_F + (w*64+nt*16+(l&15))] )
// so gemm's bfrag load is lane-consecutive 16B -> one coalesced 1KB transaction.
__global__ void wtprep_kernel(const float* __restrict__ W, unsigned short* __restrict__ Wp)
{
    int idx = blockIdx.x * blockDim.x + threadIdx.x;   // 0..32767
    int j  = idx & 7;
    int l  = (idx >> 3) & 63;
    int nt = (idx >> 9) & 3;
    int kt = (idx >> 11) & 3;
    int w  = idx >> 13;
    int k   = kt * 32 + (l >> 4) * 8 + j;
    int col = w * 64 + nt * 16 + (l & 15);
    Wp[idx] = f2bf(W[(size_t)k * OUT_F + col]);
}

// ---------------- MFMA GEMM: h(bf16) = x @ W, + per-head attention dots ----------------
__global__ __launch_bounds__(256) void gemm_mfma_kernel(
    const float* __restrict__ x, const unsigned short* __restrict__ Wp,
    const float* __restrict__ att_src, const float* __restrict__ att_dst,
    unsigned short* __restrict__ h, float* __restrict__ a_src, float* __restrict__ a_dst,
    int n)
{
    __shared__ unsigned short As[16][144];
    __shared__ unsigned short Hs[16][268];   // row stride 268 shorts: quads land on disjoint bank groups

    const int t = threadIdx.x;
    const int w = t >> 6;          // wave == head
    const int l = t & 63;
    const int quad = l >> 4;
    const int c15 = l & 15;
    const int base = blockIdx.x * 16;

    {
        const float4* xs = (const float4*)(x + (size_t)base * IN_C);
#pragma unroll
        for (int i = 0; i < 2; ++i) {
            int idx = t + i * 256;
            float4 v = xs[idx];
            int fi = idx * 4;
            int row = fi >> 7, k = fi & 127;
            ushort4 b;
            b.x = f2bf(v.x); b.y = f2bf(v.y); b.z = f2bf(v.z); b.w = f2bf(v.w);
            *(ushort4*)&As[row][k] = b;
        }
    }

    // coalesced fragment loads (1KB per wave instruction)
    short8 bfrag[4][4];
#pragma unroll
    for (int kt = 0; kt < 4; ++kt)
#pragma unroll
        for (int nt = 0; nt < 4; ++nt)
            bfrag[kt][nt] = *(const short8*)(Wp + (((w * 4 + kt) * 4 + nt) << 9) + l * 8);

    __syncthreads();

    floatx4 acc[4] = {};
#pragma unroll
    for (int kt = 0; kt < 4; ++kt) {
        int k0 = kt * 32 + quad * 8;
        short8 afrag = *(const short8*)&As[c15][k0];
#pragma unroll
        for (int nt = 0; nt < 4; ++nt)
            acc[nt] = __builtin_amdgcn_mfma_f32_16x16x32_bf16(afrag, bfrag[kt][nt], acc[nt], 0, 0, 0);
    }

    float asum[4] = {0.f, 0.f, 0.f, 0.f}, adsum[4] = {0.f, 0.f, 0.f, 0.f};
#pragma unroll
    for (int nt = 0; nt < 4; ++nt) {
        int col = w * 64 + nt * 16 + c15;
        float aw = att_src[col];
        float dw = att_dst[col];
#pragma unroll
        for (int r = 0; r < 4; ++r) {
            float v = acc[nt][r];
            Hs[quad * 4 + r][col] = f2bf(v);
            asum[r] = fmaf(v, aw, asum[r]);
            adsum[r] = fmaf(v, dw, adsum[r]);
        }
    }
#pragma unroll
    for (int r = 0; r < 4; ++r) {
        float vs = asum[r], vd = adsum[r];
#pragma unroll
        for (int m = 1; m < 16; m <<= 1) {
            vs += __shfl_xor(vs, m, 64);
            vd += __shfl_xor(vd, m, 64);
        }
        if (c15 == 0) {
            int node = base + quad * 4 + r;
            a_src[(size_t)node * HEADS + w] = vs;
            a_dst[(size_t)node * HEADS + w] = vd;
        }
    }

    __syncthreads();
#pragma unroll
    for (int i = 0; i < 2; ++i) {
        int chunk = t + i * 256;
        int si = chunk * 8;
        int row = si >> 8, c0 = si & 255;
        int4 v = *(const int4*)&Hs[row][c0];
        *(int4*)(h + (size_t)(base + row) * OUT_F + c0) = v;
    }
}

// ---------------- CSR build ----------------
__global__ void deg_kernel(const int* __restrict__ ei, int* __restrict__ deg, int E)
{
    int e = blockIdx.x * blockDim.x + threadIdx.x;
    if (e < E) atomicAdd(&deg[ei[E + e]], 1);
}

__global__ void offsets_kernel(const int* __restrict__ deg, int* __restrict__ offsets,
                               int* __restrict__ cursor, int* __restrict__ gcursor, int n)
{
    int i = blockIdx.x * blockDim.x + threadIdx.x;
    int lane = threadIdx.x & 63;
    int cnt = (i < n) ? deg[i] : 0;
    int incl = cnt;
#pragma unroll
    for (int o = 1; o < 64; o <<= 1) {
        int v = __shfl_up(incl, o, 64);
        if (lane >= o) incl += v;
    }
    int total = __shfl(incl, 63, 64);
    int base = 0;
    if (lane == 63) base = atomicAdd(gcursor, total);
    base = __shfl(base, 63, 64);
    int off = base + incl - cnt;
    if (i < n) { offsets[i] = off; cursor[i] = off; }
}

__global__ void scatter_kernel(const int* __restrict__ ei, int* __restrict__ cursor,
                               int* __restrict__ srcs, int E)
{
    int e = blockIdx.x * blockDim.x + threadIdx.x;
    if (e < E) {
        int dst = ei[E + e];
        int pos = atomicAdd(&cursor[dst], 1);
        srcs[pos] = ei[e];
    }
}

// ---------------- Aggregation: one wave per dst, masked 8x groups (no serial tail), fused BN stats ----------------
__global__ __launch_bounds__(256) void agg_kernel(
    const unsigned short* __restrict__ h, const float* __restrict__ a_src,
    const float* __restrict__ a_dst, const int* __restrict__ offsets,
    const int* __restrict__ deg, const int* __restrict__ srcs,
    const float* __restrict__ bias, float* __restrict__ out,
    float* __restrict__ sbuck, int n)
{
    __shared__ float red[2][4][OUT_F];   // 8KB: [s|s2][wave][col]

    int wave_in_blk = threadIdx.x >> 6;
    int lane = threadIdx.x & 63;
    int dst = blockIdx.x * 4 + wave_in_blk;
    int myh = lane >> 4;
    bool valid = (dst < n);

    float4 o4 = {0.f, 0.f, 0.f, 0.f};

    if (valid) {
        float adh = a_dst[(size_t)dst * HEADS + myh];

        // self loop
        float es = a_src[(size_t)dst * HEADS + myh] + adh;
        es = (es > 0.f) ? es : NEG_SLOPE * es;
        float wgt = __expf(es);
        ushort4 hv = ((const ushort4*)(h + (size_t)dst * OUT_F))[lane];
        float4 acc;
        acc.x = bf2f(hv.x) * wgt; acc.y = bf2f(hv.y) * wgt;
        acc.z = bf2f(hv.z) * wgt; acc.w = bf2f(hv.w) * wgt;
        float wsum = wgt;

        const int start = offsets[dst];
        const int cnt = deg[dst];
        // masked full-width groups: every group issues 8 independent src loads,
        // then 8 a_src + 8 h loads -> no serial-dependent tail edges.
        for (int j = 0; j < cnt; j += 8) {
            int rem = cnt - j;   // >= 1
            int last = start + j + ((rem < 8) ? rem : 8) - 1;
            int s[8];
#pragma unroll
            for (int u = 0; u < 8; ++u) {
                int idx = start + j + u;
                s[u] = srcs[(idx <= last) ? idx : last];   // clamp: duplicate load hits same line
            }
            float ew[8];
#pragma unroll
            for (int u = 0; u < 8; ++u) ew[u] = a_src[(size_t)s[u] * HEADS + myh];
            ushort4 hh[8];
#pragma unroll
            for (int u = 0; u < 8; ++u) hh[u] = ((const ushort4*)(h + (size_t)s[u] * OUT_F))[lane];
#pragma unroll
            for (int u = 0; u < 8; ++u) {
                float e = ew[u] + adh;
                e = (e > 0.f) ? e : NEG_SLOPE * e;
                float wv = __expf(e);
                wv = (u < rem) ? wv : 0.f;   // padded slots contribute exactly 0
                acc.x = fmaf(bf2f(hh[u].x), wv, acc.x);
                acc.y = fmaf(bf2f(hh[u].y), wv, acc.y);
                acc.z = fmaf(bf2f(hh[u].z), wv, acc.z);
                acc.w = fmaf(bf2f(hh[u].w), wv, acc.w);
                wsum += wv;
            }
        }

        float inv = 1.f / (wsum + 1e-16f);
        float4 b4 = ((const float4*)bias)[lane];
        o4.x = fmaf(acc.x, inv, b4.x);
        o4.y = fmaf(acc.y, inv, b4.y);
        o4.z = fmaf(acc.z, inv, b4.z);
        o4.w = fmaf(acc.w, inv, b4.w);
        ((float4*)(out + (size_t)dst * OUT_F))[lane] = o4;
    }

    // fused BN-stat accumulation (per-block reduce -> bucketed atomics)
    int c0 = lane * 4;
    *(float4*)&red[0][wave_in_blk][c0] = o4;
    float4 q4;
    q4.x = o4.x * o4.x; q4.y = o4.y * o4.y; q4.z = o4.z * o4.z; q4.w = o4.w * o4.w;
    *(float4*)&red[1][wave_in_blk][c0] = q4;
    __syncthreads();

    int t = threadIdx.x;   // column 0..255
    float s  = red[0][0][t] + red[0][1][t] + red[0][2][t] + red[0][3][t];
    float s2 = red[1][0][t] + red[1][1][t] + red[1][2][t] + red[1][3][t];
    float* bk = sbuck + (size_t)(blockIdx.x & (NBUCK - 1)) * (2 * OUT_F);
    atomicAdd(&bk[t], s);
    atomicAdd(&bk[OUT_F + t], s2);
}

// ---------------- bucket reduce -> scale/shift coefficients ----------------
__global__ void statsfinal_kernel(const float* __restrict__ sbuck,
                                  const float* __restrict__ gamma,
                                  const float* __restrict__ beta,
                                  float* __restrict__ ss, int n)
{
    int c = threadIdx.x;   // 0..255
    float s = 0.f, s2 = 0.f;
    for (int b = 0; b < NBUCK; ++b) {
        s  += sbuck[(size_t)b * (2 * OUT_F) + c];
        s2 += sbuck[(size_t)b * (2 * OUT_F) + OUT_F + c];
    }
    float invn = 1.f / (float)n;
    float mean = s * invn;
    float var = s2 * invn - mean * mean;
    float sc = gamma[c] * rsqrtf(var + BN_EPS);
    ss[c] = sc;
    ss[OUT_F + c] = beta[c] - mean * sc;
}

__device__ __forceinline__ float elu1(float v) {
    return (v > 0.f) ? v : expm1f(v);
}

__global__ __launch_bounds__(256) void bn_elu_kernel(float* __restrict__ out,
                                                     const float* __restrict__ ss,
                                                     long long n4)
{
    long long idx = (long long)blockIdx.x * blockDim.x + threadIdx.x;
    if (idx >= n4) return;
    int col4 = (int)(idx & 63);
    float4 v = ((float4*)out)[idx];
    float4 sc = ((const float4*)ss)[col4];
    float4 sh = ((const float4*)(ss + OUT_F))[col4];
    v.x = elu1(fmaf(v.x, sc.x, sh.x));
    v.y = elu1(fmaf(v.y, sc.y, sh.y));
    v.z = elu1(fmaf(v.z, sc.z, sh.z));
    v.w = elu1(fmaf(v.w, sc.w, sh.w));
    ((float4*)out)[idx] = v;
}

// ---------------- launch ----------------
extern "C" void kernel_launch(void* const* d_in, const int* in_sizes, int n_in,
                              void* d_out, int out_size, void* d_ws, size_t ws_size,
                              hipStream_t stream)
{
    const float* x       = (const float*)d_in[0];
    const int*   ei      = (const int*)d_in[1];
    const float* W       = (const float*)d_in[2];
    const float* att_src = (const float*)d_in[3];
    const float* att_dst = (const float*)d_in[4];
    const float* bias    = (const float*)d_in[5];
    const float* gamma   = (const float*)d_in[6];
    const float* beta    = (const float*)d_in[7];
    float* out = (float*)d_out;

    const int n = in_sizes[0] / IN_C;      // 100000
    const int E = in_sizes[1] / 2;         // 1600000

    float* ws = (float*)d_ws;
    size_t o = 0;
    unsigned short* h  = (unsigned short*)(ws + o); o += (size_t)n * OUT_F / 2;  // bf16
    unsigned short* Wp = (unsigned short*)(ws + o); o += IN_C * OUT_F / 2;       // bf16, frag-packed
    float* a_src  = ws + o; o += (size_t)n * HEADS;
    float* a_dst  = ws + o; o += (size_t)n * HEADS;
    float* ss     = ws + o; o += 2 * OUT_F;
    int* offsets  = (int*)(ws + o); o += n;
    int* cursor   = (int*)(ws + o); o += n;
    int* srcs     = (int*)(ws + o); o += E;
    // zero-initialized region (contiguous): deg, gcursor, sbuck
    int* deg      = (int*)(ws + o); o += n;
    int* gcursor  = (int*)(ws + o); o += 1;
    float* sbuck  = ws + o; o += (size_t)NBUCK * 2 * OUT_F;

    hipMemsetAsync(deg, 0, ((size_t)n + 1 + (size_t)NBUCK * 2 * OUT_F) * sizeof(int), stream);

    wtprep_kernel<<<(IN_C * OUT_F) / 256, 256, 0, stream>>>(W, Wp);
    gemm_mfma_kernel<<<(n + 15) / 16, 256, 0, stream>>>(x, Wp, att_src, att_dst, h, a_src, a_dst, n);
    deg_kernel<<<(E + 255) / 256, 256, 0, stream>>>(ei, deg, E);
    offsets_kernel<<<(n + 255) / 256, 256, 0, stream>>>(deg, offsets, cursor, gcursor, n);
    scatter_kernel<<<(E + 255) / 256, 256, 0, stream>>>(ei, cursor, srcs, E);
    agg_kernel<<<(n + 3) / 4, 256, 0, stream>>>(h, a_src, a_dst, offsets, deg, srcs, bias, out, sbuck, n);
    statsfinal_kernel<<<1, 256, 0, stream>>>(sbuck, gamma, beta, ss, n);
    bn_elu_kernel<<<(int)(((long long)n * 64 + 255) / 256), 256, 0, stream>>>(out, ss, (long long)n * 64);
}